// Round 4
// baseline (726.836 us; speedup 1.0000x reference)
//
#include <hip/hip_runtime.h>
#include <cstdint>
#include <cstddef>

// ---------------- problem constants ----------------
#define BTOK 65536
#define DDIM 256
#define NEXP 16
#define HDIM 256
#define ODIM 256
#define TAU2 1.2e-2f
#define TAU3 1.2e-4
#define AMB2_CAP 12288
#define AMB3_CAP 1024
#define LCAP (BTOK + 2048)

typedef _Float16 fp16x8 __attribute__((ext_vector_type(8)));
typedef float    f32x4_t __attribute__((ext_vector_type(4)));

__device__ __forceinline__ void async_ld16(const void* g, void* l) {
  __builtin_amdgcn_global_load_lds(
      (const __attribute__((address_space(1))) unsigned int*)g,
      (__attribute__((address_space(3))) unsigned int*)l, 16, 0, 0);
}

// ---------------- weight transpose + f32->f16 hi/lo ----------------
__global__ __launch_bounds__(256) void k_transpose_cvt(
    const float* __restrict__ src, _Float16* __restrict__ dhi,
    _Float16* __restrict__ dlo, int R, int C) {
  __shared__ float s[32][33];
  int bz = blockIdx.z;
  size_t stride = (size_t)R * C;
  src += (size_t)bz * stride;
  dhi += (size_t)bz * stride;
  if (dlo) dlo += (size_t)bz * stride;
  int c0 = blockIdx.x * 32, r0 = blockIdx.y * 32;
  int tx = threadIdx.x & 31, ty = threadIdx.x >> 5;
  for (int k = 0; k < 32; k += 8)
    s[ty + k][tx] = src[(size_t)(r0 + ty + k) * C + c0 + tx];
  __syncthreads();
  for (int k = 0; k < 32; k += 8) {
    float v = s[tx][ty + k];
    _Float16 h = (_Float16)v;
    size_t o = (size_t)(c0 + ty + k) * R + r0 + tx;
    dhi[o] = h;
    if (dlo) dlo[o] = (_Float16)(v - (float)h);
  }
}

// ---------------- x fp32 -> f16 hi only ----------------
__global__ __launch_bounds__(256) void k_xcvt_hi(const float* __restrict__ x,
                                                 _Float16* __restrict__ xhi, int n8) {
  int i = blockIdx.x * 256 + threadIdx.x;
  if (i >= n8) return;
  const float4* p = (const float4*)x;
  float4 a = p[(size_t)i * 2], b = p[(size_t)i * 2 + 1];
  float v[8] = {a.x, a.y, a.z, a.w, b.x, b.y, b.z, b.w};
  fp16x8 hv;
#pragma unroll
  for (int j = 0; j < 8; j++) hv[j] = (_Float16)v[j];
  *(fp16x8*)(xhi + (size_t)i * 8) = hv;
}

// ---------------- fast single-f16 GEMM: C = relu(A @ B^T + bias) f16 -------
__global__ __launch_bounds__(256) void k_gemm_f16(
    const _Float16* __restrict__ A, const _Float16* __restrict__ B,
    const float* __restrict__ bias, _Float16* __restrict__ C,
    int M, int N, int K) {
  __shared__ _Float16 sA[128 * 32], sB[128 * 32];
  const int tid = threadIdx.x;
  const int lane = tid & 63;
  const int wave = tid >> 6;
  const int wr = wave >> 1, wc = wave & 1;
  const int m0 = blockIdx.y * 128, n0 = blockIdx.x * 128;
  f32x4_t zero4 = {0.f, 0.f, 0.f, 0.f};
  f32x4_t acc[4][4];
#pragma unroll
  for (int i = 0; i < 4; i++)
#pragma unroll
    for (int j = 0; j < 4; j++) acc[i][j] = zero4;

  for (int k0 = 0; k0 < K; k0 += 32) {
#pragma unroll
    for (int r = 0; r < 2; r++) {
      int idx = r * 256 + tid;
      int row = idx >> 2, ch = idx & 3;
      int gch = ch ^ (row & 3);
      async_ld16(A + (size_t)(m0 + row) * K + k0 + gch * 8, &sA[idx * 8]);
      async_ld16(B + (size_t)(n0 + row) * K + k0 + gch * 8, &sB[idx * 8]);
    }
    __syncthreads();
    fp16x8 a[4], b[4];
    int kc = lane >> 4;
#pragma unroll
    for (int i = 0; i < 4; i++) {
      int ar = wr * 64 + i * 16 + (lane & 15);
      a[i] = *(const fp16x8*)&sA[ar * 32 + ((kc ^ (ar & 3)) << 3)];
      int br = wc * 64 + i * 16 + (lane & 15);
      b[i] = *(const fp16x8*)&sB[br * 32 + ((kc ^ (br & 3)) << 3)];
    }
#pragma unroll
    for (int i = 0; i < 4; i++)
#pragma unroll
      for (int j = 0; j < 4; j++)
        acc[i][j] = __builtin_amdgcn_mfma_f32_16x16x32_f16(a[i], b[j], acc[i][j], 0, 0, 0);
    __syncthreads();
  }
#pragma unroll
  for (int j = 0; j < 4; j++) {
    int col = n0 + wc * 64 + j * 16 + (lane & 15);
    float bc = bias[col];
#pragma unroll
    for (int i = 0; i < 4; i++)
#pragma unroll
      for (int q = 0; q < 4; q++) {
        int row = m0 + wr * 64 + i * 16 + ((lane >> 4) << 2) + q;
        float v = acc[i][j][q] + bc;
        v = v > 0.f ? v : 0.f;
        C[(size_t)row * N + col] = (_Float16)v;
      }
  }
}

// ---------------- split-f16 GEMM (tier-2): relu(A@B^T+bias), hi/lo out -----
__global__ __launch_bounds__(256) void k_gemm_split(
    const _Float16* __restrict__ Ahi, const _Float16* __restrict__ Alo,
    const _Float16* __restrict__ Bhi, const _Float16* __restrict__ Blo,
    const float* __restrict__ bias,
    _Float16* __restrict__ Chi, _Float16* __restrict__ Clo,
    int M, int N, int K, const int* __restrict__ nAct) {
  int nA = *nAct;
  if (nA > M) nA = M;
  const int m0 = blockIdx.y * 128, n0 = blockIdx.x * 128;
  if (m0 >= nA) return;
  __shared__ _Float16 sAh[128 * 32], sAl[128 * 32], sBh[128 * 32], sBl[128 * 32];
  const int tid = threadIdx.x;
  const int lane = tid & 63;
  const int wave = tid >> 6;
  const int wr = wave >> 1, wc = wave & 1;
  f32x4_t zero4 = {0.f, 0.f, 0.f, 0.f};
  f32x4_t acc[4][4];
#pragma unroll
  for (int i = 0; i < 4; i++)
#pragma unroll
    for (int j = 0; j < 4; j++) acc[i][j] = zero4;

  for (int k0 = 0; k0 < K; k0 += 32) {
#pragma unroll
    for (int r = 0; r < 2; r++) {
      int idx = r * 256 + tid;
      int row = idx >> 2, ch = idx & 3;
      int gch = ch ^ (row & 3);
      size_t ga = (size_t)(m0 + row) * K + k0 + gch * 8;
      size_t gb = (size_t)(n0 + row) * K + k0 + gch * 8;
      async_ld16(Ahi + ga, &sAh[idx * 8]);
      async_ld16(Alo + ga, &sAl[idx * 8]);
      async_ld16(Bhi + gb, &sBh[idx * 8]);
      async_ld16(Blo + gb, &sBl[idx * 8]);
    }
    __syncthreads();
    fp16x8 ah[4], al[4], bh[4], bl[4];
    int kc = lane >> 4;
#pragma unroll
    for (int i = 0; i < 4; i++) {
      int ar = wr * 64 + i * 16 + (lane & 15);
      int offa = ar * 32 + ((kc ^ (ar & 3)) << 3);
      ah[i] = *(const fp16x8*)&sAh[offa];
      al[i] = *(const fp16x8*)&sAl[offa];
      int br = wc * 64 + i * 16 + (lane & 15);
      int offb = br * 32 + ((kc ^ (br & 3)) << 3);
      bh[i] = *(const fp16x8*)&sBh[offb];
      bl[i] = *(const fp16x8*)&sBl[offb];
    }
#pragma unroll
    for (int i = 0; i < 4; i++)
#pragma unroll
      for (int j = 0; j < 4; j++) {
        acc[i][j] = __builtin_amdgcn_mfma_f32_16x16x32_f16(ah[i], bh[j], acc[i][j], 0, 0, 0);
        acc[i][j] = __builtin_amdgcn_mfma_f32_16x16x32_f16(ah[i], bl[j], acc[i][j], 0, 0, 0);
        acc[i][j] = __builtin_amdgcn_mfma_f32_16x16x32_f16(al[i], bh[j], acc[i][j], 0, 0, 0);
      }
    __syncthreads();
  }
#pragma unroll
  for (int j = 0; j < 4; j++) {
    int col = n0 + wc * 64 + j * 16 + (lane & 15);
    float bc = bias[col];
#pragma unroll
    for (int i = 0; i < 4; i++)
#pragma unroll
      for (int q = 0; q < 4; q++) {
        int row = m0 + wr * 64 + i * 16 + ((lane >> 4) << 2) + q;
        float v = acc[i][j][q] + bc;
        v = v > 0.f ? v : 0.f;
        _Float16 h = (_Float16)v;
        size_t o = (size_t)row * N + col;
        Chi[o] = h;
        Clo[o] = (_Float16)(v - (float)h);
      }
  }
}

// ------- gate layer 3 FAST: fp32 logits + top2 + flag tier-2 + histogram ---
__global__ __launch_bounds__(256) void k_gate3_fast(
    const _Float16* __restrict__ h2h, const float* __restrict__ g3,
    const float* __restrict__ gb3,
    float* __restrict__ pout, int* __restrict__ idx0, int* __restrict__ idx1,
    float* __restrict__ w0, float* __restrict__ w1,
    int* __restrict__ amb2Cnt, int* __restrict__ amb2List,
    int* __restrict__ cnt0, int* __restrict__ cnt1) {
  __shared__ _Float16 shh[16 * 256];
  __shared__ float sg3[16][260];
  __shared__ float sgb[16];
  __shared__ float slog[16][17];
  __shared__ int sidx[16][2];
  __shared__ float swv[16][2];
  __shared__ int hc0[16], hc1[16];
  int tid = threadIdx.x;
  int tokBase = blockIdx.x * 16;
  if (tid < 16) { hc0[tid] = 0; hc1[tid] = 0; }
  {
    int t = tid >> 4, c = (tid & 15) * 16;
    size_t g = (size_t)(tokBase + t) * 256 + c;
    *(fp16x8*)&shh[t * 256 + c] = *(const fp16x8*)&h2h[g];
    *(fp16x8*)&shh[t * 256 + c + 8] = *(const fp16x8*)&h2h[g + 8];
  }
#pragma unroll
  for (int r = 0; r < 16; r++) {
    int j = r * 256 + tid;
    sg3[j & 15][j >> 4] = g3[j];
  }
  if (tid < 16) sgb[tid] = gb3[tid];
  __syncthreads();
  int t = tid >> 4, e = tid & 15;
  const _Float16* ph = &shh[t * 256];
  const float* pg = &sg3[e][0];
  float acc = 0.f;
  for (int k = 0; k < 256; k += 8) {
    fp16x8 hv = *(const fp16x8*)&ph[k];
    float4 ga = *(const float4*)&pg[k];
    float4 gb = *(const float4*)&pg[k + 4];
    acc = fmaf((float)hv[0], ga.x, acc);
    acc = fmaf((float)hv[1], ga.y, acc);
    acc = fmaf((float)hv[2], ga.z, acc);
    acc = fmaf((float)hv[3], ga.w, acc);
    acc = fmaf((float)hv[4], gb.x, acc);
    acc = fmaf((float)hv[5], gb.y, acc);
    acc = fmaf((float)hv[6], gb.z, acc);
    acc = fmaf((float)hv[7], gb.w, acc);
  }
  acc += sgb[e];
  slog[t][e] = acc;
  __syncthreads();
  if (e == 0) {
    float l[16];
#pragma unroll
    for (int i = 0; i < 16; i++) l[i] = slog[t][i];
    int i1 = 0;
    for (int i = 1; i < 16; i++) if (l[i] > l[i1]) i1 = i;
    int i2 = -1;
    for (int i = 0; i < 16; i++) { if (i == i1) continue; if (i2 < 0 || l[i] > l[i2]) i2 = i; }
    float l3 = -1e30f;
    for (int i = 0; i < 16; i++) { if (i == i1 || i == i2) continue; if (l[i] > l3) l3 = l[i]; }
    float lmax = l[i1];
    float S = 0.f;
    for (int i = 0; i < 16; i++) S += expf(l[i] - lmax);
    float p1 = 1.0f / S, p2 = expf(l[i2] - lmax) / S;
    float den = p1 + p2 + 1e-9f;
    sidx[t][0] = i1; sidx[t][1] = i2;
    swv[t][0] = p1 / den; swv[t][1] = p2 / den;
    atomicAdd(&hc0[i1], 1);
    atomicAdd(&hc1[i2], 1);
    if (l[i2] - l3 < TAU2) {
      int pos = atomicAdd(amb2Cnt, 1);
      if (pos < AMB2_CAP) amb2List[pos] = tokBase + t;
    }
  }
  __syncthreads();
  int i1 = sidx[t][0], i2 = sidx[t][1];
  float pv = (e == i1) ? swv[t][0] : ((e == i2) ? swv[t][1] : 0.f);
  pout[(size_t)(tokBase + t) * 16 + e] = pv;
  if (e == 0) {
    int tok = tokBase + t;
    idx0[tok] = i1; idx1[tok] = i2;
    w0[tok] = swv[t][0]; w1[tok] = swv[t][1];
  }
  if (tid < 16) {
    if (hc0[tid]) atomicAdd(&cnt0[tid], hc0[tid]);
    if (hc1[tid]) atomicAdd(&cnt1[tid], hc1[tid]);
  }
}

// ---------------- tier-2 gather: x -> xg hi/lo ----------------
__global__ __launch_bounds__(256) void k_gather2(
    const float* __restrict__ x, const int* __restrict__ cnt,
    const int* __restrict__ list,
    _Float16* __restrict__ xgh, _Float16* __restrict__ xgl) {
  int n = *cnt; if (n > AMB2_CAP) n = AMB2_CAP;
  int s = blockIdx.x * 8 + (threadIdx.x >> 5);
  if (s >= n) return;
  int tok = list[s];
  int c = (threadIdx.x & 31) * 8;
  const float4* p = (const float4*)&x[(size_t)tok * 256 + c];
  float4 a = p[0], b = p[1];
  float v[8] = {a.x, a.y, a.z, a.w, b.x, b.y, b.z, b.w};
  fp16x8 hv, lv;
#pragma unroll
  for (int j = 0; j < 8; j++) {
    _Float16 h = (_Float16)v[j];
    hv[j] = h;
    lv[j] = (_Float16)(v[j] - (float)h);
  }
  *(fp16x8*)&xgh[(size_t)s * 256 + c] = hv;
  *(fp16x8*)&xgl[(size_t)s * 256 + c] = lv;
}

// ------- tier-2 gate3 precise: fp64 logits, overwrite + hist delta --------
__global__ __launch_bounds__(256) void k_gate3_precise(
    const _Float16* __restrict__ h2ghi, const _Float16* __restrict__ h2glo,
    const float* __restrict__ g3, const float* __restrict__ gb3,
    const int* __restrict__ amb2Cnt, const int* __restrict__ amb2List,
    float* __restrict__ pout, int* __restrict__ idx0, int* __restrict__ idx1,
    float* __restrict__ w0, float* __restrict__ w1,
    int* __restrict__ amb3Cnt, int* __restrict__ amb3List,
    int* __restrict__ cnt0, int* __restrict__ cnt1) {
  __shared__ _Float16 shh[16 * 256], shl[16 * 256];
  __shared__ float sg3[16][260];
  __shared__ float sgb[16];
  __shared__ double slog[16][17];
  __shared__ int sidx[16][2];
  __shared__ float swv[16][2];
  int tid = threadIdx.x;
  int slotBase = blockIdx.x * 16;
  int n2 = *amb2Cnt; if (n2 > AMB2_CAP) n2 = AMB2_CAP;
  {
    int t = tid >> 4, c = (tid & 15) * 16;
    size_t g = (size_t)(slotBase + t) * 256 + c;
    *(fp16x8*)&shh[t * 256 + c] = *(const fp16x8*)&h2ghi[g];
    *(fp16x8*)&shh[t * 256 + c + 8] = *(const fp16x8*)&h2ghi[g + 8];
    *(fp16x8*)&shl[t * 256 + c] = *(const fp16x8*)&h2glo[g];
    *(fp16x8*)&shl[t * 256 + c + 8] = *(const fp16x8*)&h2glo[g + 8];
  }
#pragma unroll
  for (int r = 0; r < 16; r++) {
    int j = r * 256 + tid;
    sg3[j & 15][j >> 4] = g3[j];
  }
  if (tid < 16) sgb[tid] = gb3[tid];
  __syncthreads();
  int t = tid >> 4, e = tid & 15;
  int slot = slotBase + t;
  const _Float16* ph = &shh[t * 256];
  const _Float16* pl = &shl[t * 256];
  const float* pg = &sg3[e][0];
  double acc = 0.0;
  for (int k = 0; k < 256; k += 4) {
#pragma unroll
    for (int j = 0; j < 4; j++) {
      double a = (double)(float)ph[k + j] + (double)(float)pl[k + j];
      acc = fma(a, (double)pg[k + j], acc);
    }
  }
  acc += (double)sgb[e];
  slog[t][e] = acc;
  __syncthreads();
  if (e == 0 && slot < n2) {
    int tok = amb2List[slot];
    double l[16];
#pragma unroll
    for (int i = 0; i < 16; i++) l[i] = slog[t][i];
    int i1 = 0;
    for (int i = 1; i < 16; i++) if (l[i] > l[i1]) i1 = i;
    int i2 = -1;
    for (int i = 0; i < 16; i++) { if (i == i1) continue; if (i2 < 0 || l[i] > l[i2]) i2 = i; }
    double l3 = -1e300;
    for (int i = 0; i < 16; i++) { if (i == i1 || i == i2) continue; if (l[i] > l3) l3 = l[i]; }
    double lmax = l[i1];
    double S = 0.0;
    for (int i = 0; i < 16; i++) S += exp(l[i] - lmax);
    double p1 = 1.0 / S, p2 = exp(l[i2] - lmax) / S;
    double den = p1 + p2 + 1e-9;
    sidx[t][0] = i1; sidx[t][1] = i2;
    swv[t][0] = (float)(p1 / den); swv[t][1] = (float)(p2 / den);
    int o0 = idx0[tok], o1 = idx1[tok];
    if (i1 != o0) { atomicSub(&cnt0[o0], 1); atomicAdd(&cnt0[i1], 1); }
    if (i2 != o1) { atomicSub(&cnt1[o1], 1); atomicAdd(&cnt1[i2], 1); }
    if (l[i2] - l3 < TAU3) {
      int pos = atomicAdd(amb3Cnt, 1);
      if (pos < AMB3_CAP) amb3List[pos] = tok;
    }
  }
  __syncthreads();
  if (slot < n2) {
    int tok = amb2List[slot];
    int i1 = sidx[t][0], i2 = sidx[t][1];
    float pv = (e == i1) ? swv[t][0] : ((e == i2) ? swv[t][1] : 0.f);
    pout[(size_t)tok * 16 + e] = pv;
    if (e == 0) {
      idx0[tok] = i1; idx1[tok] = i2;
      w0[tok] = swv[t][0]; w1[tok] = swv[t][1];
    }
  }
}

// ---------------- tier-3 batched fp64: L1 ----------------
__global__ __launch_bounds__(256) void k_ref_l1(
    const float* __restrict__ x, const float* __restrict__ g1,
    const float* __restrict__ gb1,
    const int* __restrict__ cnt, const int* __restrict__ list,
    double* __restrict__ h1d) {
  int n = *cnt; if (n > AMB3_CAP) n = AMB3_CAP;
  int t = blockIdx.y;
  if (t >= n) return;
  __shared__ float sx[256];
  __shared__ double sred[4][64];
  int tid = threadIdx.x;
  int tok = list[t];
  sx[tid] = x[(size_t)tok * 256 + tid];
  __syncthreads();
  int o = tid & 63, p = tid >> 6;
  int out = blockIdx.x * 64 + o;
  double a = 0.0;
  const float* gp = g1 + (size_t)(p * 64) * 1024 + out;
  const float* xp = &sx[p * 64];
#pragma unroll 8
  for (int k = 0; k < 64; k++)
    a = fma((double)xp[k], (double)gp[(size_t)k * 1024], a);
  sred[p][o] = a;
  __syncthreads();
  if (p == 0) {
    double s = sred[0][o] + sred[1][o] + sred[2][o] + sred[3][o] + (double)gb1[out];
    h1d[(size_t)t * 1024 + out] = s > 0.0 ? s : 0.0;
  }
}

// ---------------- tier-3 batched fp64: L2 ----------------
__global__ __launch_bounds__(512) void k_ref_l2(
    const double* __restrict__ h1d, const float* __restrict__ g2,
    const float* __restrict__ gb2,
    const int* __restrict__ cnt, double* __restrict__ h2d) {
  int n = *cnt; if (n > AMB3_CAP) n = AMB3_CAP;
  int t = blockIdx.y;
  if (t >= n) return;
  __shared__ double sh1[1024];
  __shared__ double sred[8][64];
  int tid = threadIdx.x;
  sh1[tid] = h1d[(size_t)t * 1024 + tid];
  sh1[512 + tid] = h1d[(size_t)t * 1024 + 512 + tid];
  __syncthreads();
  int o = tid & 63, p = tid >> 6;
  int out = blockIdx.x * 64 + o;
  double a = 0.0;
  const float* gp = g2 + (size_t)(p * 128) * 256 + out;
  const double* hp = &sh1[p * 128];
#pragma unroll 4
  for (int k = 0; k < 128; k++)
    a = fma(hp[k], (double)gp[(size_t)k * 256], a);
  sred[p][o] = a;
  __syncthreads();
  if (p == 0) {
    double s = sred[0][o] + sred[1][o] + sred[2][o] + sred[3][o] +
               sred[4][o] + sred[5][o] + sred[6][o] + sred[7][o] + (double)gb2[out];
    h2d[(size_t)t * 256 + out] = s > 0.0 ? s : 0.0;
  }
}

// ---------------- tier-3: L3 + decide + hist delta ----------------
__global__ __launch_bounds__(256) void k_ref_l3(
    const double* __restrict__ h2d, const float* __restrict__ g3,
    const float* __restrict__ gb3,
    const int* __restrict__ cnt, const int* __restrict__ list,
    float* __restrict__ pout, int* __restrict__ idx0, int* __restrict__ idx1,
    float* __restrict__ w0, float* __restrict__ w1,
    int* __restrict__ cnt0, int* __restrict__ cnt1) {
  int n = *cnt; if (n > AMB3_CAP) n = AMB3_CAP;
  int t = blockIdx.x;
  if (t >= n) return;
  __shared__ double sh2[256];
  __shared__ double sl16[16][17];
  __shared__ int sidx[2];
  __shared__ float swv[2];
  int tid = threadIdx.x;
  int tok = list[t];
  sh2[tid] = h2d[(size_t)t * 256 + tid];
  __syncthreads();
  {
    int o = tid & 15, pp = tid >> 4;
    double a = 0.0;
#pragma unroll
    for (int k = pp * 16; k < pp * 16 + 16; k++)
      a = fma(sh2[k], (double)g3[(size_t)k * 16 + o], a);
    sl16[pp][o] = a;
  }
  __syncthreads();
  if (tid == 0) {
    double l[16];
    for (int o = 0; o < 16; o++) {
      double a = (double)gb3[o];
      for (int p = 0; p < 16; p++) a += sl16[p][o];
      l[o] = a;
    }
    int i1 = 0;
    for (int i = 1; i < 16; i++) if (l[i] > l[i1]) i1 = i;
    int i2 = -1;
    for (int i = 0; i < 16; i++) { if (i == i1) continue; if (i2 < 0 || l[i] > l[i2]) i2 = i; }
    double lmax = l[i1];
    double S = 0.0;
    for (int i = 0; i < 16; i++) S += exp(l[i] - lmax);
    double p1 = 1.0 / S, p2 = exp(l[i2] - lmax) / S;
    double den = p1 + p2 + 1e-9;
    float fw0 = (float)(p1 / den), fw1 = (float)(p2 / den);
    int o0 = idx0[tok], o1 = idx1[tok];
    if (i1 != o0) { atomicSub(&cnt0[o0], 1); atomicAdd(&cnt0[i1], 1); }
    if (i2 != o1) { atomicSub(&cnt1[o1], 1); atomicAdd(&cnt1[i2], 1); }
    sidx[0] = i1; sidx[1] = i2;
    swv[0] = fw0; swv[1] = fw1;
    idx0[tok] = i1; idx1[tok] = i2;
    w0[tok] = fw0; w1[tok] = fw1;
  }
  __syncthreads();
  if (tid < 16) {
    float pv = (tid == sidx[0]) ? swv[0] : ((tid == sidx[1]) ? swv[1] : 0.f);
    pout[(size_t)tok * 16 + tid] = pv;
  }
}

// ---------------- offsets: build combined tile list ----------------
__global__ void k_offsets(const int* __restrict__ cnt0, const int* __restrict__ cnt1,
                          int* off0, int* off1, int* cur0, int* cur1,
                          int* dExpC, int* dRowC, int* nTiles) {
  if (threadIdx.x == 0) {
    int tot = 0, nt = 0;
    for (int e = 0; e < 16; e++) {
      off0[e] = tot; cur0[e] = 0;
      int tiles = (cnt0[e] + 127) >> 7;
      for (int ti = 0; ti < tiles; ti++) { dExpC[nt] = e; dRowC[nt] = tot + ti * 128; nt++; }
      tot += tiles * 128;
    }
    nTiles[0] = nt;
    tot = 0;
    for (int e = 0; e < 16; e++) {
      off1[e] = tot; cur1[e] = 0;
      int tiles = (cnt1[e] + 127) >> 7;
      for (int ti = 0; ti < tiles; ti++) { dExpC[nt] = e; dRowC[nt] = LCAP + tot + ti * 128; nt++; }
      tot += tiles * 128;
    }
    nTiles[1] = nt;
  }
}

__global__ __launch_bounds__(256) void k_scatter(
    const int* __restrict__ idx0, const int* __restrict__ idx1,
    const float* __restrict__ w0, const float* __restrict__ w1,
    const int* __restrict__ off0, const int* __restrict__ off1,
    int* cur0, int* cur1,
    int* __restrict__ tok0, float* __restrict__ wl0,
    int* __restrict__ tok1, float* __restrict__ wl1) {
  __shared__ int c0[16], c1[16], b0[16], b1[16];
  int tid = threadIdx.x;
  if (tid < 16) { c0[tid] = 0; c1[tid] = 0; }
  __syncthreads();
  int b = blockIdx.x * 256 + tid;
  int e0 = idx0[b], e1 = idx1[b];
  int r0 = atomicAdd(&c0[e0], 1);
  int r1 = atomicAdd(&c1[e1], 1);
  __syncthreads();
  if (tid < 16) { b0[tid] = atomicAdd(&cur0[tid], c0[tid]); b1[tid] = atomicAdd(&cur1[tid], c1[tid]); }
  __syncthreads();
  int p0 = off0[e0] + b0[e0] + r0;
  tok0[p0] = b; wl0[p0] = w0[b];
  int p1 = off1[e1] + b1[e1] + r1;
  tok1[p1] = b; wl1[p1] = w1[b];
}

// ---------------- grouped GEMM L1: heg = relu((x+bias) @ W1^T + b1) --------
__global__ __launch_bounds__(512) void k_grp_l1(
    const _Float16* __restrict__ xhi, const float* __restrict__ bias,
    const _Float16* __restrict__ W1T, const float* __restrict__ b1,
    const int* __restrict__ tokAll,
    const int* __restrict__ dExp, const int* __restrict__ dRow,
    const int* __restrict__ nT, _Float16* __restrict__ heg) {
  __shared__ _Float16 sA[128 * 32];
  __shared__ _Float16 sB[256 * 32];
  __shared__ int sTok[128];
  __shared__ float sBias[256];
  int tid = threadIdx.x, lane = tid & 63, wave = tid >> 6;
  int wr = wave >> 2, wc = wave & 3;   // 2 x 4 waves -> 128 x 256 tile
  f32x4_t zero4 = {0.f, 0.f, 0.f, 0.f};
  int nt = *nT;
  for (int t = blockIdx.x; t < nt; t += gridDim.x) {
    int e = dExp[t], rowOff = dRow[t];
    if (tid < 128) sTok[tid] = tokAll[rowOff + tid];
    if (tid < 256) sBias[tid] = bias[e * 256 + tid];
    __syncthreads();
    f32x4_t acc[4][4];
#pragma unroll
    for (int i = 0; i < 4; i++)
#pragma unroll
      for (int j = 0; j < 4; j++) acc[i][j] = zero4;
    const _Float16* W1e = W1T + (size_t)e * 65536;
    for (int k0 = 0; k0 < 256; k0 += 32) {
      {  // stage A: gathered x + bias, reg-staged (swizzled content, linear dest)
        int row = tid >> 2, ch = tid & 3, gch = ch ^ (row & 3);
        int tok = sTok[row];
        int tk = tok < 0 ? 0 : tok;
        fp16x8 v = *(const fp16x8*)&xhi[(size_t)tk * 256 + k0 + gch * 8];
        const float* bp = &sBias[k0 + gch * 8];
#pragma unroll
        for (int j = 0; j < 8; j++) v[j] = (_Float16)((float)v[j] + bp[j]);
        *(fp16x8*)&sA[tid * 8] = v;
      }
#pragma unroll
      for (int r = 0; r < 2; r++) {  // stage B: W1 rows via global_load_lds
        int idx = r * 512 + tid;
        int row = idx >> 2, ch = idx & 3, gch = ch ^ (row & 3);
        async_ld16(W1e + (size_t)row * 256 + k0 + gch * 8, &sB[idx * 8]);
      }
      __syncthreads();
      fp16x8 a[4], b[4];
      int kc = lane >> 4;
#pragma unroll
      for (int i = 0; i < 4; i++) {
        int ar = wr * 64 + i * 16 + (lane & 15);
        a[i] = *(const fp16x8*)&sA[ar * 32 + ((kc ^ (ar & 3)) << 3)];
        int br = wc * 64 + i * 16 + (lane & 15);
        b[i] = *(const fp16x8*)&sB[br * 32 + ((kc ^ (br & 3)) << 3)];
      }
#pragma unroll
      for (int i = 0; i < 4; i++)
#pragma unroll
        for (int j = 0; j < 4; j++)
          acc[i][j] = __builtin_amdgcn_mfma_f32_16x16x32_f16(a[i], b[j], acc[i][j], 0, 0, 0);
      __syncthreads();
    }
#pragma unroll
    for (int j = 0; j < 4; j++) {
      int col = wc * 64 + j * 16 + (lane & 15);
      float bb = b1[e * 256 + col];
#pragma unroll
      for (int i = 0; i < 4; i++)
#pragma unroll
        for (int q = 0; q < 4; q++) {
          int row = wr * 64 + i * 16 + ((lane >> 4) << 2) + q;
          float v = acc[i][j][q] + bb;
          heg[(size_t)(rowOff + row) * 256 + col] = (_Float16)(v > 0.f ? v : 0.f);
        }
    }
    __syncthreads();
  }
}

// ------ grouped GEMM L2: y (=/+=) (heg @ W2^T + b2) * w ------
template <int PASSB>
__global__ __launch_bounds__(512) void k_grp_l2(
    const _Float16* __restrict__ heg, const _Float16* __restrict__ W2T,
    const float* __restrict__ b2,
    const int* __restrict__ tokAll, const float* __restrict__ wlAll,
    const int* __restrict__ dExp, const int* __restrict__ dRow,
    const int* __restrict__ nT0, const int* __restrict__ nTC,
    float* __restrict__ y) {
  __shared__ _Float16 sA[128 * 32];
  __shared__ _Float16 sB[256 * 32];
  __shared__ int sTok[128];
  __shared__ float sW[128];
  int tid = threadIdx.x, lane = tid & 63, wave = tid >> 6;
  int wr = wave >> 2, wc = wave & 3;
  f32x4_t zero4 = {0.f, 0.f, 0.f, 0.f};
  int tStart = PASSB ? *nT0 : 0;
  int tEnd = PASSB ? *nTC : *nT0;
  for (int t = tStart + blockIdx.x; t < tEnd; t += gridDim.x) {
    int e = dExp[t], rowOff = dRow[t];
    if (tid < 128) { sTok[tid] = tokAll[rowOff + tid]; sW[tid] = wlAll[rowOff + tid]; }
    __syncthreads();
    f32x4_t acc[4][4];
#pragma unroll
    for (int i = 0; i < 4; i++)
#pragma unroll
      for (int j = 0; j < 4; j++) acc[i][j] = zero4;
    const _Float16* W2e = W2T + (size_t)e * 65536;
    for (int k0 = 0; k0 < 256; k0 += 32) {
      {  // stage A: heg rows are contiguous -> direct async
        int row = tid >> 2, ch = tid & 3, gch = ch ^ (row & 3);
        async_ld16(heg + (size_t)(rowOff + row) * 256 + k0 + gch * 8, &sA[tid * 8]);
      }
#pragma unroll
      for (int r = 0; r < 2; r++) {
        int idx = r * 512 + tid;
        int row = idx >> 2, ch = idx & 3, gch = ch ^ (row & 3);
        async_ld16(W2e + (size_t)row * 256 + k0 + gch * 8, &sB[idx * 8]);
      }
      __syncthreads();
      fp16x8 a[4], b[4];
      int kc = lane >> 4;
#pragma unroll
      for (int i = 0; i < 4; i++) {
        int ar = wr * 64 + i * 16 + (lane & 15);
        a[i] = *(const fp16x8*)&sA[ar * 32 + ((kc ^ (ar & 3)) << 3)];
        int br = wc * 64 + i * 16 + (lane & 15);
        b[i] = *(const fp16x8*)&sB[br * 32 + ((kc ^ (br & 3)) << 3)];
      }
#pragma unroll
      for (int i = 0; i < 4; i++)
#pragma unroll
        for (int j = 0; j < 4; j++)
          acc[i][j] = __builtin_amdgcn_mfma_f32_16x16x32_f16(a[i], b[j], acc[i][j], 0, 0, 0);
      __syncthreads();
    }
#pragma unroll
    for (int j = 0; j < 4; j++) {
      int col = wc * 64 + j * 16 + (lane & 15);
      float bb = b2[e * 256 + col];
#pragma unroll
      for (int i = 0; i < 4; i++)
#pragma unroll
        for (int q = 0; q < 4; q++) {
          int row = wr * 64 + i * 16 + ((lane >> 4) << 2) + q;
          int tok = sTok[row];
          if (tok >= 0) {
            float v = (acc[i][j][q] + bb) * sW[row];
            size_t o = (size_t)tok * 256 + col;
            if (PASSB) y[o] += v; else y[o] = v;
          }
        }
    }
    __syncthreads();
  }
}

// ---------------- host-side orchestration ----------------
extern "C" void kernel_launch(void* const* d_in, const int* in_sizes, int n_in,
                              void* d_out, int out_size, void* d_ws, size_t ws_size,
                              hipStream_t stream) {
  const float* x   = (const float*)d_in[0];
  const float* bias= (const float*)d_in[1];
  const float* W1  = (const float*)d_in[2];
  const float* b1  = (const float*)d_in[3];
  const float* W2  = (const float*)d_in[4];
  const float* b2  = (const float*)d_in[5];
  const float* g1  = (const float*)d_in[6];
  const float* gb1 = (const float*)d_in[7];
  const float* g2  = (const float*)d_in[8];
  const float* gb2 = (const float*)d_in[9];
  const float* g3  = (const float*)d_in[10];
  const float* gb3 = (const float*)d_in[11];
  float* y    = (float*)d_out;
  float* pout = y + (size_t)BTOK * 256;

  char* w = (char*)d_ws;
  auto alloc = [&](size_t bytes) -> char* {
    char* p = w;
    w += (bytes + 255) & ~(size_t)255;
    return p;
  };
  _Float16* xhi  = (_Float16*)alloc((size_t)BTOK * 256 * 2);
  _Float16* h2h  = (_Float16*)alloc((size_t)BTOK * 256 * 2);
  _Float16* g1Th = (_Float16*)alloc((size_t)256 * 1024 * 2);
  _Float16* g1Tl = (_Float16*)alloc((size_t)256 * 1024 * 2);
  _Float16* g2Th = (_Float16*)alloc((size_t)256 * 1024 * 2);
  _Float16* g2Tl = (_Float16*)alloc((size_t)256 * 1024 * 2);
  _Float16* W1T  = (_Float16*)alloc((size_t)16 * 65536 * 2);
  _Float16* W2T  = (_Float16*)alloc((size_t)16 * 65536 * 2);
  int*   idx0 = (int*)alloc((size_t)BTOK * 4);
  int*   idx1 = (int*)alloc((size_t)BTOK * 4);
  float* w0a  = (float*)alloc((size_t)BTOK * 4);
  float* w1a  = (float*)alloc((size_t)BTOK * 4);
  int*   ctrl = (int*)alloc(4096);
  int*   amb2List = (int*)alloc((size_t)AMB2_CAP * 4);
  int*   amb3List = (int*)alloc((size_t)AMB3_CAP * 4);
  int*   dExpC = (int*)alloc(1088 * 4);
  int*   dRowC = (int*)alloc(1088 * 4);
  int*   tokAll = (int*)alloc((size_t)2 * LCAP * 4);
  float* wlAll  = (float*)alloc((size_t)2 * LCAP * 4);
  // tier-2 buffers (dead before the expert phase; heg aliases this region)
  _Float16* xgh  = (_Float16*)alloc((size_t)AMB2_CAP * 256 * 2);
  _Float16* xgl  = (_Float16*)alloc((size_t)AMB2_CAP * 256 * 2);
  _Float16* h1gh = (_Float16*)alloc((size_t)AMB2_CAP * 1024 * 2);
  _Float16* h1gl = (_Float16*)alloc((size_t)AMB2_CAP * 1024 * 2);
  _Float16* h2gh = (_Float16*)alloc((size_t)AMB2_CAP * 256 * 2);
  _Float16* h2gl = (_Float16*)alloc((size_t)AMB2_CAP * 256 * 2);
  // heg aliases the tier-2 block: needs 2*LCAP*256*2 = 69.2 MB <= 75.5 MB
  _Float16* heg = (_Float16*)xgh;
  // tier-3 fp64 intermediates
  double* h1d = (double*)alloc((size_t)AMB3_CAP * 1024 * 8);
  double* h2d = (double*)alloc((size_t)AMB3_CAP * 256 * 8);

  size_t used = (size_t)(w - (char*)d_ws);
  size_t remain = ws_size > used ? ws_size - used : 0;
  int CG = 1;
  while (CG < 64 && (size_t)(BTOK / CG) * 1024 * 2 + 1024 > remain) CG <<= 1;
  int MC = BTOK / CG;
  _Float16* h1h = (_Float16*)alloc((size_t)MC * 1024 * 2);

  int* cnt0 = ctrl + 0;  int* cnt1 = ctrl + 16;
  int* off0 = ctrl + 32; int* off1 = ctrl + 48;
  int* cur0 = ctrl + 64; int* cur1 = ctrl + 80;
  int* nTiles = ctrl + 96;
  int* amb2Cnt = ctrl + 112;
  int* amb3Cnt = ctrl + 116;

  hipMemsetAsync(ctrl, 0, 4096, stream);
  hipMemsetAsync(tokAll, 0xFF, (size_t)2 * LCAP * 4, stream);

  dim3 tb(256);
  k_transpose_cvt<<<dim3(32, 8, 1), tb, 0, stream>>>(g1, g1Th, g1Tl, 256, 1024);
  k_transpose_cvt<<<dim3(8, 32, 1), tb, 0, stream>>>(g2, g2Th, g2Tl, 1024, 256);
  k_transpose_cvt<<<dim3(8, 8, 16), tb, 0, stream>>>(W1, W1T, nullptr, 256, 256);
  k_transpose_cvt<<<dim3(8, 8, 16), tb, 0, stream>>>(W2, W2T, nullptr, 256, 256);
  k_xcvt_hi<<<(BTOK * 256 / 8 + 255) / 256, tb, 0, stream>>>(x, xhi, BTOK * 256 / 8);

  // ---- fast gate (single f16) ----
  for (int c = 0; c < CG; c++) {
    const _Float16* xh = xhi + (size_t)c * MC * 256;
    k_gemm_f16<<<dim3(8, MC / 128), tb, 0, stream>>>(xh, g1Th, gb1, h1h, MC, 1024, 256);
    k_gemm_f16<<<dim3(2, MC / 128), tb, 0, stream>>>(h1h, g2Th, gb2,
                                                     h2h + (size_t)c * MC * 256, MC, 256, 1024);
  }
  k_gate3_fast<<<BTOK / 16, tb, 0, stream>>>(h2h, g3, gb3, pout, idx0, idx1,
                                             w0a, w1a, amb2Cnt, amb2List, cnt0, cnt1);

  // ---- tier-2: split-f16 precise gate on near-tie tokens ----
  k_gather2<<<AMB2_CAP / 8, tb, 0, stream>>>(x, amb2Cnt, amb2List, xgh, xgl);
  k_gemm_split<<<dim3(8, AMB2_CAP / 128), tb, 0, stream>>>(
      xgh, xgl, g1Th, g1Tl, gb1, h1gh, h1gl, AMB2_CAP, 1024, 256, amb2Cnt);
  k_gemm_split<<<dim3(2, AMB2_CAP / 128), tb, 0, stream>>>(
      h1gh, h1gl, g2Th, g2Tl, gb2, h2gh, h2gl, AMB2_CAP, 256, 1024, amb2Cnt);
  k_gate3_precise<<<AMB2_CAP / 16, tb, 0, stream>>>(
      h2gh, h2gl, g3, gb3, amb2Cnt, amb2List, pout, idx0, idx1, w0a, w1a,
      amb3Cnt, amb3List, cnt0, cnt1);

  // ---- tier-3: batched parallel fp64 ----
  k_ref_l1<<<dim3(16, AMB3_CAP), tb, 0, stream>>>(x, g1, gb1, amb3Cnt, amb3List, h1d);
  k_ref_l2<<<dim3(4, AMB3_CAP), 512, 0, stream>>>(h1d, g2, gb2, amb3Cnt, h2d);
  k_ref_l3<<<AMB3_CAP, tb, 0, stream>>>(h2d, g3, gb3, amb3Cnt, amb3List,
                                        pout, idx0, idx1, w0a, w1a, cnt0, cnt1);

  // ---- bucket + grouped expert GEMMs ----
  k_offsets<<<1, 64, 0, stream>>>(cnt0, cnt1, off0, off1, cur0, cur1,
                                  dExpC, dRowC, nTiles);
  k_scatter<<<BTOK / 256, tb, 0, stream>>>(idx0, idx1, w0a, w1a, off0, off1,
                                           cur0, cur1, tokAll, wlAll,
                                           tokAll + LCAP, wlAll + LCAP);
  k_grp_l1<<<1056, 512, 0, stream>>>(xhi, bias, W1T, b1, tokAll,
                                     dExpC, dRowC, nTiles + 1, heg);
  k_grp_l2<0><<<528, 512, 0, stream>>>(heg, W2T, b2, tokAll, wlAll,
                                       dExpC, dRowC, nTiles, nTiles + 1, y);
  k_grp_l2<1><<<528, 512, 0, stream>>>(heg, W2T, b2, tokAll, wlAll,
                                       dExpC, dRowC, nTiles, nTiles + 1, y);
}

// Round 8
// 648.652 us; speedup vs baseline: 1.1205x; 1.1205x over previous
//
#include <hip/hip_runtime.h>
#include <cstdint>
#include <cstddef>

// ---------------- problem constants ----------------
#define BTOK 65536
#define DDIM 256
#define NEXP 16
#define HDIM 256
#define ODIM 256
#define TAU2 1.2e-2f
#define TAU3 1.2e-4
#define AMB2_CAP 12288
#define AMB3_CAP 1024
#define LCAP (BTOK + 2048)

typedef _Float16 fp16x8 __attribute__((ext_vector_type(8)));
typedef float    f32x4_t __attribute__((ext_vector_type(4)));

__device__ __forceinline__ void async_ld16(const void* g, void* l) {
  __builtin_amdgcn_global_load_lds(
      (const __attribute__((address_space(1))) unsigned int*)g,
      (__attribute__((address_space(3))) unsigned int*)l, 16, 0, 0);
}

// ---------------- weight transpose + f32->f16 hi/lo ----------------
__global__ __launch_bounds__(256) void k_transpose_cvt(
    const float* __restrict__ src, _Float16* __restrict__ dhi,
    _Float16* __restrict__ dlo, int R, int C) {
  __shared__ float s[32][33];
  int bz = blockIdx.z;
  size_t stride = (size_t)R * C;
  src += (size_t)bz * stride;
  dhi += (size_t)bz * stride;
  if (dlo) dlo += (size_t)bz * stride;
  int c0 = blockIdx.x * 32, r0 = blockIdx.y * 32;
  int tx = threadIdx.x & 31, ty = threadIdx.x >> 5;
  for (int k = 0; k < 32; k += 8)
    s[ty + k][tx] = src[(size_t)(r0 + ty + k) * C + c0 + tx];
  __syncthreads();
  for (int k = 0; k < 32; k += 8) {
    float v = s[tx][ty + k];
    _Float16 h = (_Float16)v;
    size_t o = (size_t)(c0 + ty + k) * R + r0 + tx;
    dhi[o] = h;
    if (dlo) dlo[o] = (_Float16)(v - (float)h);
  }
}

// ---------------- g3 [256][16] f32 -> g3T [16][256] f16 ----------------
__global__ __launch_bounds__(256) void k_g3cvt(const float* __restrict__ g3,
                                               _Float16* __restrict__ g3T) {
  int idx = blockIdx.x * 256 + threadIdx.x;  // 4096
  int k = idx >> 4, e = idx & 15;
  g3T[e * 256 + k] = (_Float16)g3[idx];
}

// ---------------- x fp32 -> f16 hi only ----------------
__global__ __launch_bounds__(256) void k_xcvt_hi(const float* __restrict__ x,
                                                 _Float16* __restrict__ xhi, int n8) {
  int i = blockIdx.x * 256 + threadIdx.x;
  if (i >= n8) return;
  const float4* p = (const float4*)x;
  float4 a = p[(size_t)i * 2], b = p[(size_t)i * 2 + 1];
  float v[8] = {a.x, a.y, a.z, a.w, b.x, b.y, b.z, b.w};
  fp16x8 hv;
#pragma unroll
  for (int j = 0; j < 8; j++) hv[j] = (_Float16)v[j];
  *(fp16x8*)(xhi + (size_t)i * 8) = hv;
}

// ---------------- fast single-f16 GEMM: C = relu(A @ B^T + bias) f16 -------
__global__ __launch_bounds__(256) void k_gemm_f16(
    const _Float16* __restrict__ A, const _Float16* __restrict__ B,
    const float* __restrict__ bias, _Float16* __restrict__ C,
    int M, int N, int K) {
  __shared__ _Float16 sA[128 * 32], sB[128 * 32];
  const int tid = threadIdx.x;
  const int lane = tid & 63;
  const int wave = tid >> 6;
  const int wr = wave >> 1, wc = wave & 1;
  const int m0 = blockIdx.y * 128, n0 = blockIdx.x * 128;
  f32x4_t zero4 = {0.f, 0.f, 0.f, 0.f};
  f32x4_t acc[4][4];
#pragma unroll
  for (int i = 0; i < 4; i++)
#pragma unroll
    for (int j = 0; j < 4; j++) acc[i][j] = zero4;

  for (int k0 = 0; k0 < K; k0 += 32) {
#pragma unroll
    for (int r = 0; r < 2; r++) {
      int idx = r * 256 + tid;
      int row = idx >> 2, ch = idx & 3;
      int gch = ch ^ (row & 3);
      async_ld16(A + (size_t)(m0 + row) * K + k0 + gch * 8, &sA[idx * 8]);
      async_ld16(B + (size_t)(n0 + row) * K + k0 + gch * 8, &sB[idx * 8]);
    }
    __syncthreads();
    fp16x8 a[4], b[4];
    int kc = lane >> 4;
#pragma unroll
    for (int i = 0; i < 4; i++) {
      int ar = wr * 64 + i * 16 + (lane & 15);
      a[i] = *(const fp16x8*)&sA[ar * 32 + ((kc ^ (ar & 3)) << 3)];
      int br = wc * 64 + i * 16 + (lane & 15);
      b[i] = *(const fp16x8*)&sB[br * 32 + ((kc ^ (br & 3)) << 3)];
    }
#pragma unroll
    for (int i = 0; i < 4; i++)
#pragma unroll
      for (int j = 0; j < 4; j++)
        acc[i][j] = __builtin_amdgcn_mfma_f32_16x16x32_f16(a[i], b[j], acc[i][j], 0, 0, 0);
    __syncthreads();
  }
#pragma unroll
  for (int j = 0; j < 4; j++) {
    int col = n0 + wc * 64 + j * 16 + (lane & 15);
    float bc = bias[col];
#pragma unroll
    for (int i = 0; i < 4; i++)
#pragma unroll
      for (int q = 0; q < 4; q++) {
        int row = m0 + wr * 64 + i * 16 + ((lane >> 4) << 2) + q;
        float v = acc[i][j][q] + bc;
        v = v > 0.f ? v : 0.f;
        C[(size_t)row * N + col] = (_Float16)v;
      }
  }
}

// ---------------- split-f16 GEMM (tier-2): relu(A@B^T+bias), hi/lo out -----
__global__ __launch_bounds__(256) void k_gemm_split(
    const _Float16* __restrict__ Ahi, const _Float16* __restrict__ Alo,
    const _Float16* __restrict__ Bhi, const _Float16* __restrict__ Blo,
    const float* __restrict__ bias,
    _Float16* __restrict__ Chi, _Float16* __restrict__ Clo,
    int M, int N, int K, const int* __restrict__ nAct) {
  int nA = *nAct;
  if (nA > M) nA = M;
  const int m0 = blockIdx.y * 128, n0 = blockIdx.x * 128;
  if (m0 >= nA) return;
  __shared__ _Float16 sAh[128 * 32], sAl[128 * 32], sBh[128 * 32], sBl[128 * 32];
  const int tid = threadIdx.x;
  const int lane = tid & 63;
  const int wave = tid >> 6;
  const int wr = wave >> 1, wc = wave & 1;
  f32x4_t zero4 = {0.f, 0.f, 0.f, 0.f};
  f32x4_t acc[4][4];
#pragma unroll
  for (int i = 0; i < 4; i++)
#pragma unroll
    for (int j = 0; j < 4; j++) acc[i][j] = zero4;

  for (int k0 = 0; k0 < K; k0 += 32) {
#pragma unroll
    for (int r = 0; r < 2; r++) {
      int idx = r * 256 + tid;
      int row = idx >> 2, ch = idx & 3;
      int gch = ch ^ (row & 3);
      size_t ga = (size_t)(m0 + row) * K + k0 + gch * 8;
      size_t gb = (size_t)(n0 + row) * K + k0 + gch * 8;
      async_ld16(Ahi + ga, &sAh[idx * 8]);
      async_ld16(Alo + ga, &sAl[idx * 8]);
      async_ld16(Bhi + gb, &sBh[idx * 8]);
      async_ld16(Blo + gb, &sBl[idx * 8]);
    }
    __syncthreads();
    fp16x8 ah[4], al[4], bh[4], bl[4];
    int kc = lane >> 4;
#pragma unroll
    for (int i = 0; i < 4; i++) {
      int ar = wr * 64 + i * 16 + (lane & 15);
      int offa = ar * 32 + ((kc ^ (ar & 3)) << 3);
      ah[i] = *(const fp16x8*)&sAh[offa];
      al[i] = *(const fp16x8*)&sAl[offa];
      int br = wc * 64 + i * 16 + (lane & 15);
      int offb = br * 32 + ((kc ^ (br & 3)) << 3);
      bh[i] = *(const fp16x8*)&sBh[offb];
      bl[i] = *(const fp16x8*)&sBl[offb];
    }
#pragma unroll
    for (int i = 0; i < 4; i++)
#pragma unroll
      for (int j = 0; j < 4; j++) {
        acc[i][j] = __builtin_amdgcn_mfma_f32_16x16x32_f16(ah[i], bh[j], acc[i][j], 0, 0, 0);
        acc[i][j] = __builtin_amdgcn_mfma_f32_16x16x32_f16(ah[i], bl[j], acc[i][j], 0, 0, 0);
        acc[i][j] = __builtin_amdgcn_mfma_f32_16x16x32_f16(al[i], bh[j], acc[i][j], 0, 0, 0);
      }
    __syncthreads();
  }
#pragma unroll
  for (int j = 0; j < 4; j++) {
    int col = n0 + wc * 64 + j * 16 + (lane & 15);
    float bc = bias[col];
#pragma unroll
    for (int i = 0; i < 4; i++)
#pragma unroll
      for (int q = 0; q < 4; q++) {
        int row = m0 + wr * 64 + i * 16 + ((lane >> 4) << 2) + q;
        float v = acc[i][j][q] + bc;
        v = v > 0.f ? v : 0.f;
        _Float16 h = (_Float16)v;
        size_t o = (size_t)row * N + col;
        Chi[o] = h;
        Clo[o] = (_Float16)(v - (float)h);
      }
  }
}

// ---------------- gate L3 logits via MFMA: logits = h2 @ g3 + gb3 ----------
__global__ __launch_bounds__(256) void k_logits(
    const _Float16* __restrict__ h2h, const _Float16* __restrict__ g3T,
    const float* __restrict__ gb3, float* __restrict__ logits) {
  __shared__ _Float16 sA[128 * 32];
  __shared__ _Float16 sG[16 * 264];
  int tid = threadIdx.x, lane = tid & 63, wave = tid >> 6;
  int m0 = blockIdx.x * 128;
  {
    int r = tid >> 4, c = (tid & 15) * 16;
    *(fp16x8*)&sG[r * 264 + c]     = *(const fp16x8*)&g3T[r * 256 + c];
    *(fp16x8*)&sG[r * 264 + c + 8] = *(const fp16x8*)&g3T[r * 256 + c + 8];
  }
  f32x4_t zero4 = {0.f, 0.f, 0.f, 0.f};
  f32x4_t acc[2] = {zero4, zero4};
  for (int k0 = 0; k0 < 256; k0 += 32) {
#pragma unroll
    for (int r = 0; r < 2; r++) {
      int idx = r * 256 + tid;
      int row = idx >> 2, ch = idx & 3, gch = ch ^ (row & 3);
      async_ld16(h2h + (size_t)(m0 + row) * 256 + k0 + gch * 8, &sA[idx * 8]);
    }
    __syncthreads();
    int kc = lane >> 4;
    fp16x8 b = *(const fp16x8*)&sG[(lane & 15) * 264 + k0 + kc * 8];
#pragma unroll
    for (int i = 0; i < 2; i++) {
      int ar = wave * 32 + i * 16 + (lane & 15);
      fp16x8 a = *(const fp16x8*)&sA[ar * 32 + ((kc ^ (ar & 3)) << 3)];
      acc[i] = __builtin_amdgcn_mfma_f32_16x16x32_f16(a, b, acc[i], 0, 0, 0);
    }
    __syncthreads();
  }
  float bb = gb3[lane & 15];
#pragma unroll
  for (int i = 0; i < 2; i++)
#pragma unroll
    for (int q = 0; q < 4; q++) {
      int row = m0 + wave * 32 + i * 16 + ((lane >> 4) << 2) + q;
      logits[(size_t)row * 16 + (lane & 15)] = acc[i][q] + bb;
    }
}

// ------- top2 + softmax + renorm + tier-2 flag + histogram (1 thr/token) ---
__global__ __launch_bounds__(256) void k_top2(
    const float* __restrict__ logits,
    float* __restrict__ pout, int* __restrict__ idx0, int* __restrict__ idx1,
    float* __restrict__ w0, float* __restrict__ w1,
    int* __restrict__ amb2Cnt, int* __restrict__ amb2List,
    int* __restrict__ cnt0, int* __restrict__ cnt1) {
  __shared__ int hc0[16], hc1[16];
  int tid = threadIdx.x;
  if (tid < 16) { hc0[tid] = 0; hc1[tid] = 0; }
  __syncthreads();
  int tok = blockIdx.x * 256 + tid;
  const float4* lp = (const float4*)&logits[(size_t)tok * 16];
  float4 v0 = lp[0], v1 = lp[1], v2 = lp[2], v3 = lp[3];
  float l[16] = {v0.x, v0.y, v0.z, v0.w, v1.x, v1.y, v1.z, v1.w,
                 v2.x, v2.y, v2.z, v2.w, v3.x, v3.y, v3.z, v3.w};
  float l1v = -1e30f; int i1 = -1;
#pragma unroll
  for (int e = 0; e < 16; e++) if (l[e] > l1v) { l1v = l[e]; i1 = e; }
  float l2v = -1e30f; int i2 = -1;
#pragma unroll
  for (int e = 0; e < 16; e++) if (e != i1 && l[e] > l2v) { l2v = l[e]; i2 = e; }
  float l3v = -1e30f;
#pragma unroll
  for (int e = 0; e < 16; e++) if (e != i1 && e != i2 && l[e] > l3v) l3v = l[e];
  float S = 0.f;
#pragma unroll
  for (int e = 0; e < 16; e++) S += expf(l[e] - l1v);
  float p1 = 1.0f / S, p2 = expf(l2v - l1v) / S;
  float den = p1 + p2 + 1e-9f;
  float W0 = p1 / den, W1v = p2 / den;
  float4* po = (float4*)&pout[(size_t)tok * 16];
#pragma unroll
  for (int g = 0; g < 4; g++) {
    float4 o;
    o.x = (g * 4 + 0 == i1) ? W0 : ((g * 4 + 0 == i2) ? W1v : 0.f);
    o.y = (g * 4 + 1 == i1) ? W0 : ((g * 4 + 1 == i2) ? W1v : 0.f);
    o.z = (g * 4 + 2 == i1) ? W0 : ((g * 4 + 2 == i2) ? W1v : 0.f);
    o.w = (g * 4 + 3 == i1) ? W0 : ((g * 4 + 3 == i2) ? W1v : 0.f);
    po[g] = o;
  }
  idx0[tok] = i1; idx1[tok] = i2;
  w0[tok] = W0; w1[tok] = W1v;
  atomicAdd(&hc0[i1], 1);
  atomicAdd(&hc1[i2], 1);
  if (l2v - l3v < TAU2) {
    int pos = atomicAdd(amb2Cnt, 1);
    if (pos < AMB2_CAP) amb2List[pos] = tok;
  }
  __syncthreads();
  if (tid < 16) { atomicAdd(&cnt0[tid], hc0[tid]); atomicAdd(&cnt1[tid], hc1[tid]); }
}

// ---------------- tier-2 gather: x -> xg hi/lo ----------------
__global__ __launch_bounds__(256) void k_gather2(
    const float* __restrict__ x, const int* __restrict__ cnt,
    const int* __restrict__ list,
    _Float16* __restrict__ xgh, _Float16* __restrict__ xgl) {
  int n = *cnt; if (n > AMB2_CAP) n = AMB2_CAP;
  int s = blockIdx.x * 8 + (threadIdx.x >> 5);
  if (s >= n) return;
  int tok = list[s];
  int c = (threadIdx.x & 31) * 8;
  const float4* p = (const float4*)&x[(size_t)tok * 256 + c];
  float4 a = p[0], b = p[1];
  float v[8] = {a.x, a.y, a.z, a.w, b.x, b.y, b.z, b.w};
  fp16x8 hv, lv;
#pragma unroll
  for (int j = 0; j < 8; j++) {
    _Float16 h = (_Float16)v[j];
    hv[j] = h;
    lv[j] = (_Float16)(v[j] - (float)h);
  }
  *(fp16x8*)&xgh[(size_t)s * 256 + c] = hv;
  *(fp16x8*)&xgl[(size_t)s * 256 + c] = lv;
}

// ------- tier-2 gate3 precise: fp64 logits, overwrite + hist delta --------
__global__ __launch_bounds__(256) void k_gate3_precise(
    const _Float16* __restrict__ h2ghi, const _Float16* __restrict__ h2glo,
    const float* __restrict__ g3, const float* __restrict__ gb3,
    const int* __restrict__ amb2Cnt, const int* __restrict__ amb2List,
    float* __restrict__ pout, int* __restrict__ idx0, int* __restrict__ idx1,
    float* __restrict__ w0, float* __restrict__ w1,
    int* __restrict__ amb3Cnt, int* __restrict__ amb3List,
    int* __restrict__ cnt0, int* __restrict__ cnt1) {
  __shared__ _Float16 shh[16 * 256], shl[16 * 256];
  __shared__ float sg3[16][260];
  __shared__ float sgb[16];
  __shared__ double slog[16][17];
  __shared__ int sidx[16][2];
  __shared__ float swv[16][2];
  int tid = threadIdx.x;
  int slotBase = blockIdx.x * 16;
  int n2 = *amb2Cnt; if (n2 > AMB2_CAP) n2 = AMB2_CAP;
  {
    int t = tid >> 4, c = (tid & 15) * 16;
    size_t g = (size_t)(slotBase + t) * 256 + c;
    *(fp16x8*)&shh[t * 256 + c] = *(const fp16x8*)&h2ghi[g];
    *(fp16x8*)&shh[t * 256 + c + 8] = *(const fp16x8*)&h2ghi[g + 8];
    *(fp16x8*)&shl[t * 256 + c] = *(const fp16x8*)&h2glo[g];
    *(fp16x8*)&shl[t * 256 + c + 8] = *(const fp16x8*)&h2glo[g + 8];
  }
#pragma unroll
  for (int r = 0; r < 16; r++) {
    int j = r * 256 + tid;
    sg3[j & 15][j >> 4] = g3[j];
  }
  if (tid < 16) sgb[tid] = gb3[tid];
  __syncthreads();
  int t = tid >> 4, e = tid & 15;
  int slot = slotBase + t;
  const _Float16* ph = &shh[t * 256];
  const _Float16* pl = &shl[t * 256];
  const float* pg = &sg3[e][0];
  double acc = 0.0;
  for (int k = 0; k < 256; k += 4) {
#pragma unroll
    for (int j = 0; j < 4; j++) {
      double a = (double)(float)ph[k + j] + (double)(float)pl[k + j];
      acc = fma(a, (double)pg[k + j], acc);
    }
  }
  acc += (double)sgb[e];
  slog[t][e] = acc;
  __syncthreads();
  if (e == 0 && slot < n2) {
    int tok = amb2List[slot];
    double l[16];
#pragma unroll
    for (int i = 0; i < 16; i++) l[i] = slog[t][i];
    int i1 = 0;
    for (int i = 1; i < 16; i++) if (l[i] > l[i1]) i1 = i;
    int i2 = -1;
    for (int i = 0; i < 16; i++) { if (i == i1) continue; if (i2 < 0 || l[i] > l[i2]) i2 = i; }
    double l3 = -1e300;
    for (int i = 0; i < 16; i++) { if (i == i1 || i == i2) continue; if (l[i] > l3) l3 = l[i]; }
    double lmax = l[i1];
    double S = 0.0;
    for (int i = 0; i < 16; i++) S += exp(l[i] - lmax);
    double p1 = 1.0 / S, p2 = exp(l[i2] - lmax) / S;
    double den = p1 + p2 + 1e-9;
    sidx[t][0] = i1; sidx[t][1] = i2;
    swv[t][0] = (float)(p1 / den); swv[t][1] = (float)(p2 / den);
    int o0 = idx0[tok], o1 = idx1[tok];
    if (i1 != o0) { atomicSub(&cnt0[o0], 1); atomicAdd(&cnt0[i1], 1); }
    if (i2 != o1) { atomicSub(&cnt1[o1], 1); atomicAdd(&cnt1[i2], 1); }
    if (l[i2] - l3 < TAU3) {
      int pos = atomicAdd(amb3Cnt, 1);
      if (pos < AMB3_CAP) amb3List[pos] = tok;
    }
  }
  __syncthreads();
  if (slot < n2) {
    int tok = amb2List[slot];
    int i1 = sidx[t][0], i2 = sidx[t][1];
    float pv = (e == i1) ? swv[t][0] : ((e == i2) ? swv[t][1] : 0.f);
    pout[(size_t)tok * 16 + e] = pv;
    if (e == 0) {
      idx0[tok] = i1; idx1[tok] = i2;
      w0[tok] = swv[t][0]; w1[tok] = swv[t][1];
    }
  }
}

// ---------------- tier-3 batched fp64: L1 ----------------
__global__ __launch_bounds__(256) void k_ref_l1(
    const float* __restrict__ x, const float* __restrict__ g1,
    const float* __restrict__ gb1,
    const int* __restrict__ cnt, const int* __restrict__ list,
    double* __restrict__ h1d) {
  int n = *cnt; if (n > AMB3_CAP) n = AMB3_CAP;
  int t = blockIdx.y;
  if (t >= n) return;
  __shared__ float sx[256];
  __shared__ double sred[4][64];
  int tid = threadIdx.x;
  int tok = list[t];
  sx[tid] = x[(size_t)tok * 256 + tid];
  __syncthreads();
  int o = tid & 63, p = tid >> 6;
  int out = blockIdx.x * 64 + o;
  double a = 0.0;
  const float* gp = g1 + (size_t)(p * 64) * 1024 + out;
  const float* xp = &sx[p * 64];
#pragma unroll 8
  for (int k = 0; k < 64; k++)
    a = fma((double)xp[k], (double)gp[(size_t)k * 1024], a);
  sred[p][o] = a;
  __syncthreads();
  if (p == 0) {
    double s = sred[0][o] + sred[1][o] + sred[2][o] + sred[3][o] + (double)gb1[out];
    h1d[(size_t)t * 1024 + out] = s > 0.0 ? s : 0.0;
  }
}

// ---------------- tier-3 batched fp64: L2 ----------------
__global__ __launch_bounds__(512) void k_ref_l2(
    const double* __restrict__ h1d, const float* __restrict__ g2,
    const float* __restrict__ gb2,
    const int* __restrict__ cnt, double* __restrict__ h2d) {
  int n = *cnt; if (n > AMB3_CAP) n = AMB3_CAP;
  int t = blockIdx.y;
  if (t >= n) return;
  __shared__ double sh1[1024];
  __shared__ double sred[8][64];
  int tid = threadIdx.x;
  sh1[tid] = h1d[(size_t)t * 1024 + tid];
  sh1[512 + tid] = h1d[(size_t)t * 1024 + 512 + tid];
  __syncthreads();
  int o = tid & 63, p = tid >> 6;
  int out = blockIdx.x * 64 + o;
  double a = 0.0;
  const float* gp = g2 + (size_t)(p * 128) * 256 + out;
  const double* hp = &sh1[p * 128];
#pragma unroll 4
  for (int k = 0; k < 128; k++)
    a = fma(hp[k], (double)gp[(size_t)k * 256], a);
  sred[p][o] = a;
  __syncthreads();
  if (p == 0) {
    double s = sred[0][o] + sred[1][o] + sred[2][o] + sred[3][o] +
               sred[4][o] + sred[5][o] + sred[6][o] + sred[7][o] + (double)gb2[out];
    h2d[(size_t)t * 256 + out] = s > 0.0 ? s : 0.0;
  }
}

// ---------------- tier-3: L3 + decide + hist delta ----------------
__global__ __launch_bounds__(256) void k_ref_l3(
    const double* __restrict__ h2d, const float* __restrict__ g3,
    const float* __restrict__ gb3,
    const int* __restrict__ cnt, const int* __restrict__ list,
    float* __restrict__ pout, int* __restrict__ idx0, int* __restrict__ idx1,
    float* __restrict__ w0, float* __restrict__ w1,
    int* __restrict__ cnt0, int* __restrict__ cnt1) {
  int n = *cnt; if (n > AMB3_CAP) n = AMB3_CAP;
  int t = blockIdx.x;
  if (t >= n) return;
  __shared__ double sh2[256];
  __shared__ double sl16[16][17];
  __shared__ int sidx[2];
  __shared__ float swv[2];
  int tid = threadIdx.x;
  int tok = list[t];
  sh2[tid] = h2d[(size_t)t * 256 + tid];
  __syncthreads();
  {
    int o = tid & 15, pp = tid >> 4;
    double a = 0.0;
#pragma unroll
    for (int k = pp * 16; k < pp * 16 + 16; k++)
      a = fma(sh2[k], (double)g3[(size_t)k * 16 + o], a);
    sl16[pp][o] = a;
  }
  __syncthreads();
  if (tid == 0) {
    double l[16];
    for (int o = 0; o < 16; o++) {
      double a = (double)gb3[o];
      for (int p = 0; p < 16; p++) a += sl16[p][o];
      l[o] = a;
    }
    int i1 = 0;
    for (int i = 1; i < 16; i++) if (l[i] > l[i1]) i1 = i;
    int i2 = -1;
    for (int i = 0; i < 16; i++) { if (i == i1) continue; if (i2 < 0 || l[i] > l[i2]) i2 = i; }
    double lmax = l[i1];
    double S = 0.0;
    for (int i = 0; i < 16; i++) S += exp(l[i] - lmax);
    double p1 = 1.0 / S, p2 = exp(l[i2] - lmax) / S;
    double den = p1 + p2 + 1e-9;
    float fw0 = (float)(p1 / den), fw1 = (float)(p2 / den);
    int o0 = idx0[tok], o1 = idx1[tok];
    if (i1 != o0) { atomicSub(&cnt0[o0], 1); atomicAdd(&cnt0[i1], 1); }
    if (i2 != o1) { atomicSub(&cnt1[o1], 1); atomicAdd(&cnt1[i2], 1); }
    sidx[0] = i1; sidx[1] = i2;
    swv[0] = fw0; swv[1] = fw1;
    idx0[tok] = i1; idx1[tok] = i2;
    w0[tok] = fw0; w1[tok] = fw1;
  }
  __syncthreads();
  if (tid < 16) {
    float pv = (tid == sidx[0]) ? swv[0] : ((tid == sidx[1]) ? swv[1] : 0.f);
    pout[(size_t)tok * 16 + tid] = pv;
  }
}

// ---------------- offsets: build combined tile list ----------------
__global__ void k_offsets(const int* __restrict__ cnt0, const int* __restrict__ cnt1,
                          int* off0, int* off1, int* cur0, int* cur1,
                          int* dExpC, int* dRowC, int* nTiles) {
  if (threadIdx.x == 0) {
    int tot = 0, nt = 0;
    for (int e = 0; e < 16; e++) {
      off0[e] = tot; cur0[e] = 0;
      int tiles = (cnt0[e] + 127) >> 7;
      for (int ti = 0; ti < tiles; ti++) { dExpC[nt] = e; dRowC[nt] = tot + ti * 128; nt++; }
      tot += tiles * 128;
    }
    nTiles[0] = nt;
    tot = 0;
    for (int e = 0; e < 16; e++) {
      off1[e] = tot; cur1[e] = 0;
      int tiles = (cnt1[e] + 127) >> 7;
      for (int ti = 0; ti < tiles; ti++) { dExpC[nt] = e; dRowC[nt] = LCAP + tot + ti * 128; nt++; }
      tot += tiles * 128;
    }
    nTiles[1] = nt;
  }
}

__global__ __launch_bounds__(256) void k_scatter(
    const int* __restrict__ idx0, const int* __restrict__ idx1,
    const float* __restrict__ w0, const float* __restrict__ w1,
    const int* __restrict__ off0, const int* __restrict__ off1,
    int* cur0, int* cur1,
    int* __restrict__ tok0, float* __restrict__ wl0,
    int* __restrict__ tok1, float* __restrict__ wl1) {
  __shared__ int c0[16], c1[16], b0[16], b1[16];
  int tid = threadIdx.x;
  if (tid < 16) { c0[tid] = 0; c1[tid] = 0; }
  __syncthreads();
  int b = blockIdx.x * 256 + tid;
  int e0 = idx0[b], e1 = idx1[b];
  int r0 = atomicAdd(&c0[e0], 1);
  int r1 = atomicAdd(&c1[e1], 1);
  __syncthreads();
  if (tid < 16) { b0[tid] = atomicAdd(&cur0[tid], c0[tid]); b1[tid] = atomicAdd(&cur1[tid], c1[tid]); }
  __syncthreads();
  int p0 = off0[e0] + b0[e0] + r0;
  tok0[p0] = b; wl0[p0] = w0[b];
  int p1 = off1[e1] + b1[e1] + r1;
  tok1[p1] = b; wl1[p1] = w1[b];
}

// ---------------- grouped GEMM L1: heg = relu((x+bias) @ W1^T + b1) --------
__global__ __launch_bounds__(512) void k_grp_l1(
    const _Float16* __restrict__ xhi, const float* __restrict__ bias,
    const _Float16* __restrict__ W1T, const float* __restrict__ b1,
    const int* __restrict__ tokAll,
    const int* __restrict__ dExp, const int* __restrict__ dRow,
    const int* __restrict__ nT, _Float16* __restrict__ heg) {
  __shared__ _Float16 sA[128 * 32];
  __shared__ _Float16 sB[256 * 32];
  __shared__ int sTok[128];
  __shared__ float sBias[256];
  __shared__ float sB1c[256];
  __shared__ _Float16 sOutH[16 * 268];
  int tid = threadIdx.x, lane = tid & 63, wave = tid >> 6;
  int wr = wave >> 2, wc = wave & 3;   // 2 x 4 waves -> 128 x 256 tile
  f32x4_t zero4 = {0.f, 0.f, 0.f, 0.f};
  int nt = *nT;
  for (int t = blockIdx.x; t < nt; t += gridDim.x) {
    int e = dExp[t], rowOff = dRow[t];
    if (tid < 128) sTok[tid] = tokAll[rowOff + tid];
    if (tid < 256) { sBias[tid] = bias[e * 256 + tid]; sB1c[tid] = b1[e * 256 + tid]; }
    __syncthreads();
    f32x4_t acc[4][4];
#pragma unroll
    for (int i = 0; i < 4; i++)
#pragma unroll
      for (int j = 0; j < 4; j++) acc[i][j] = zero4;
    const _Float16* W1e = W1T + (size_t)e * 65536;
    for (int k0 = 0; k0 < 256; k0 += 32) {
      {  // stage A: gathered x + bias, reg-staged
        int row = tid >> 2, ch = tid & 3, gch = ch ^ (row & 3);
        int tok = sTok[row];
        int tk = tok < 0 ? 0 : tok;
        fp16x8 v = *(const fp16x8*)&xhi[(size_t)tk * 256 + k0 + gch * 8];
        const float* bp = &sBias[k0 + gch * 8];
#pragma unroll
        for (int j = 0; j < 8; j++) v[j] = (_Float16)((float)v[j] + bp[j]);
        *(fp16x8*)&sA[tid * 8] = v;
      }
#pragma unroll
      for (int r = 0; r < 2; r++) {  // stage B: W1 rows via global_load_lds
        int idx = r * 512 + tid;
        int row = idx >> 2, ch = idx & 3, gch = ch ^ (row & 3);
        async_ld16(W1e + (size_t)row * 256 + k0 + gch * 8, &sB[idx * 8]);
      }
      __syncthreads();
      fp16x8 a[4], b[4];
      int kc = lane >> 4;
#pragma unroll
      for (int i = 0; i < 4; i++) {
        int ar = wr * 64 + i * 16 + (lane & 15);
        a[i] = *(const fp16x8*)&sA[ar * 32 + ((kc ^ (ar & 3)) << 3)];
        int br = wc * 64 + i * 16 + (lane & 15);
        b[i] = *(const fp16x8*)&sB[br * 32 + ((kc ^ (br & 3)) << 3)];
      }
#pragma unroll
      for (int i = 0; i < 4; i++)
#pragma unroll
        for (int j = 0; j < 4; j++)
          acc[i][j] = __builtin_amdgcn_mfma_f32_16x16x32_f16(a[i], b[j], acc[i][j], 0, 0, 0);
      __syncthreads();
    }
    // epilogue: LDS transpose -> coalesced full-row f16 stores
#pragma unroll
    for (int wrg = 0; wrg < 2; wrg++) {
#pragma unroll
      for (int i = 0; i < 4; i++) {
        __syncthreads();
        if (wr == wrg) {
#pragma unroll
          for (int j = 0; j < 4; j++) {
            float bb = sB1c[wc * 64 + j * 16 + (lane & 15)];
#pragma unroll
            for (int q = 0; q < 4; q++) {
              int rowc = ((lane >> 4) << 2) + q;
              float v = acc[i][j][q] + bb;
              v = v > 0.f ? v : 0.f;
              sOutH[rowc * 268 + wc * 64 + j * 16 + (lane & 15)] = (_Float16)v;
            }
          }
        }
        __syncthreads();
        int rowc = tid >> 5, seg = tid & 31;
        int row128 = wrg * 64 + i * 16 + rowc;
        fp16x8 hv = *(const fp16x8*)&sOutH[rowc * 268 + seg * 8];
        *(fp16x8*)&heg[(size_t)(rowOff + row128) * 256 + seg * 8] = hv;
      }
    }
    __syncthreads();
  }
}

// ------ grouped GEMM L2: y (=/+=) (heg @ W2^T + b2) * w ------
template <int PASSB>
__global__ __launch_bounds__(512) void k_grp_l2(
    const _Float16* __restrict__ heg, const _Float16* __restrict__ W2T,
    const float* __restrict__ b2,
    const int* __restrict__ tokAll, const float* __restrict__ wlAll,
    const int* __restrict__ dExp, const int* __restrict__ dRow,
    const int* __restrict__ nT0, const int* __restrict__ nTC,
    float* __restrict__ y) {
  __shared__ _Float16 sA[128 * 32];
  __shared__ _Float16 sB[256 * 32];
  __shared__ int sTok[128];
  __shared__ float sW[128];
  __shared__ float sB2c[256];
  __shared__ float sOut[16 * 266];
  int tid = threadIdx.x, lane = tid & 63, wave = tid >> 6;
  int wr = wave >> 2, wc = wave & 3;
  f32x4_t zero4 = {0.f, 0.f, 0.f, 0.f};
  int tStart = PASSB ? *nT0 : 0;
  int tEnd = PASSB ? *nTC : *nT0;
  for (int t = tStart + blockIdx.x; t < tEnd; t += gridDim.x) {
    int e = dExp[t], rowOff = dRow[t];
    if (tid < 128) { sTok[tid] = tokAll[rowOff + tid]; sW[tid] = wlAll[rowOff + tid]; }
    if (tid < 256) sB2c[tid] = b2[e * 256 + tid];
    __syncthreads();
    f32x4_t acc[4][4];
#pragma unroll
    for (int i = 0; i < 4; i++)
#pragma unroll
      for (int j = 0; j < 4; j++) acc[i][j] = zero4;
    const _Float16* W2e = W2T + (size_t)e * 65536;
    for (int k0 = 0; k0 < 256; k0 += 32) {
      {  // stage A: heg rows contiguous -> direct async
        int row = tid >> 2, ch = tid & 3, gch = ch ^ (row & 3);
        async_ld16(heg + (size_t)(rowOff + row) * 256 + k0 + gch * 8, &sA[tid * 8]);
      }
#pragma unroll
      for (int r = 0; r < 2; r++) {
        int idx = r * 512 + tid;
        int row = idx >> 2, ch = idx & 3, gch = ch ^ (row & 3);
        async_ld16(W2e + (size_t)row * 256 + k0 + gch * 8, &sB[idx * 8]);
      }
      __syncthreads();
      fp16x8 a[4], b[4];
      int kc = lane >> 4;
#pragma unroll
      for (int i = 0; i < 4; i++) {
        int ar = wr * 64 + i * 16 + (lane & 15);
        a[i] = *(const fp16x8*)&sA[ar * 32 + ((kc ^ (ar & 3)) << 3)];
        int br = wc * 64 + i * 16 + (lane & 15);
        b[i] = *(const fp16x8*)&sB[br * 32 + ((kc ^ (br & 3)) << 3)];
      }
#pragma unroll
      for (int i = 0; i < 4; i++)
#pragma unroll
        for (int j = 0; j < 4; j++)
          acc[i][j] = __builtin_amdgcn_mfma_f32_16x16x32_f16(a[i], b[j], acc[i][j], 0, 0, 0);
      __syncthreads();
    }
    // epilogue: LDS transpose -> coalesced full-row float4 stores (RMW for PASSB)
#pragma unroll
    for (int wrg = 0; wrg < 2; wrg++) {
#pragma unroll
      for (int i = 0; i < 4; i++) {
        __syncthreads();
        if (wr == wrg) {
#pragma unroll
          for (int j = 0; j < 4; j++) {
            float bb = sB2c[wc * 64 + j * 16 + (lane & 15)];
#pragma unroll
            for (int q = 0; q < 4; q++) {
              int rowc = ((lane >> 4) << 2) + q;
              int row128 = wrg * 64 + i * 16 + rowc;
              sOut[rowc * 266 + wc * 64 + j * 16 + (lane & 15)] =
                  (acc[i][j][q] + bb) * sW[row128];
            }
          }
        }
        __syncthreads();
        int rowc = tid >> 5, seg = tid & 31;
        int row128 = wrg * 64 + i * 16 + rowc;
        int tok = sTok[row128];
        if (tok >= 0) {
          float4 v0 = *(const float4*)&sOut[rowc * 266 + seg * 8];
          float4 v1 = *(const float4*)&sOut[rowc * 266 + seg * 8 + 4];
          float* yp = &y[(size_t)tok * 256 + seg * 8];
          if (PASSB) {
            float4 o0 = *(const float4*)yp;
            float4 o1 = *(const float4*)(yp + 4);
            v0.x += o0.x; v0.y += o0.y; v0.z += o0.z; v0.w += o0.w;
            v1.x += o1.x; v1.y += o1.y; v1.z += o1.z; v1.w += o1.w;
          }
          *(float4*)yp = v0;
          *(float4*)(yp + 4) = v1;
        }
      }
    }
    __syncthreads();
  }
}

// ---------------- host-side orchestration ----------------
extern "C" void kernel_launch(void* const* d_in, const int* in_sizes, int n_in,
                              void* d_out, int out_size, void* d_ws, size_t ws_size,
                              hipStream_t stream) {
  const float* x   = (const float*)d_in[0];
  const float* bias= (const float*)d_in[1];
  const float* W1  = (const float*)d_in[2];
  const float* b1  = (const float*)d_in[3];
  const float* W2  = (const float*)d_in[4];
  const float* b2  = (const float*)d_in[5];
  const float* g1  = (const float*)d_in[6];
  const float* gb1 = (const float*)d_in[7];
  const float* g2  = (const float*)d_in[8];
  const float* gb2 = (const float*)d_in[9];
  const float* g3  = (const float*)d_in[10];
  const float* gb3 = (const float*)d_in[11];
  float* y    = (float*)d_out;
  float* pout = y + (size_t)BTOK * 256;

  char* w = (char*)d_ws;
  auto alloc = [&](size_t bytes) -> char* {
    char* p = w;
    w += (bytes + 255) & ~(size_t)255;
    return p;
  };
  _Float16* xhi  = (_Float16*)alloc((size_t)BTOK * 256 * 2);
  _Float16* h2h  = (_Float16*)alloc((size_t)BTOK * 256 * 2);
  _Float16* g1Th = (_Float16*)alloc((size_t)256 * 1024 * 2);
  _Float16* g1Tl = (_Float16*)alloc((size_t)256 * 1024 * 2);
  _Float16* g2Th = (_Float16*)alloc((size_t)256 * 1024 * 2);
  _Float16* g2Tl = (_Float16*)alloc((size_t)256 * 1024 * 2);
  _Float16* g3Th = (_Float16*)alloc((size_t)16 * 256 * 2);
  _Float16* W1T  = (_Float16*)alloc((size_t)16 * 65536 * 2);
  _Float16* W2T  = (_Float16*)alloc((size_t)16 * 65536 * 2);
  float* logits = (float*)alloc((size_t)BTOK * 16 * 4);
  int*   idx0 = (int*)alloc((size_t)BTOK * 4);
  int*   idx1 = (int*)alloc((size_t)BTOK * 4);
  float* w0a  = (float*)alloc((size_t)BTOK * 4);
  float* w1a  = (float*)alloc((size_t)BTOK * 4);
  int*   ctrl = (int*)alloc(4096);
  int*   amb2List = (int*)alloc((size_t)AMB2_CAP * 4);
  int*   amb3List = (int*)alloc((size_t)AMB3_CAP * 4);
  int*   dExpC = (int*)alloc(1088 * 4);
  int*   dRowC = (int*)alloc(1088 * 4);
  int*   tokAll = (int*)alloc((size_t)2 * LCAP * 4);
  float* wlAll  = (float*)alloc((size_t)2 * LCAP * 4);
  // tier-2 buffers (dead before the expert phase; heg aliases this region)
  _Float16* xgh  = (_Float16*)alloc((size_t)AMB2_CAP * 256 * 2);
  _Float16* xgl  = (_Float16*)alloc((size_t)AMB2_CAP * 256 * 2);
  _Float16* h1gh = (_Float16*)alloc((size_t)AMB2_CAP * 1024 * 2);
  _Float16* h1gl = (_Float16*)alloc((size_t)AMB2_CAP * 1024 * 2);
  _Float16* h2gh = (_Float16*)alloc((size_t)AMB2_CAP * 256 * 2);
  _Float16* h2gl = (_Float16*)alloc((size_t)AMB2_CAP * 256 * 2);
  _Float16* heg = (_Float16*)xgh;  // aliases tier-2 block (69.2 MB <= 75.5 MB)
  // tier-3 fp64 intermediates
  double* h1d = (double*)alloc((size_t)AMB3_CAP * 1024 * 8);
  double* h2d = (double*)alloc((size_t)AMB3_CAP * 256 * 8);

  size_t used = (size_t)(w - (char*)d_ws);
  size_t remain = ws_size > used ? ws_size - used : 0;
  int CG = 1;
  while (CG < 64 && (size_t)(BTOK / CG) * 1024 * 2 + 1024 > remain) CG <<= 1;
  int MC = BTOK / CG;
  _Float16* h1h = (_Float16*)alloc((size_t)MC * 1024 * 2);

  int* cnt0 = ctrl + 0;  int* cnt1 = ctrl + 16;
  int* off0 = ctrl + 32; int* off1 = ctrl + 48;
  int* cur0 = ctrl + 64; int* cur1 = ctrl + 80;
  int* nTiles = ctrl + 96;
  int* amb2Cnt = ctrl + 112;
  int* amb3Cnt = ctrl + 116;

  hipMemsetAsync(ctrl, 0, 4096, stream);
  hipMemsetAsync(tokAll, 0xFF, (size_t)2 * LCAP * 4, stream);

  dim3 tb(256);
  k_transpose_cvt<<<dim3(32, 8, 1), tb, 0, stream>>>(g1, g1Th, g1Tl, 256, 1024);
  k_transpose_cvt<<<dim3(8, 32, 1), tb, 0, stream>>>(g2, g2Th, g2Tl, 1024, 256);
  k_transpose_cvt<<<dim3(8, 8, 16), tb, 0, stream>>>(W1, W1T, nullptr, 256, 256);
  k_transpose_cvt<<<dim3(8, 8, 16), tb, 0, stream>>>(W2, W2T, nullptr, 256, 256);
  k_g3cvt<<<16, tb, 0, stream>>>(g3, g3Th);
  k_xcvt_hi<<<(BTOK * 256 / 8 + 255) / 256, tb, 0, stream>>>(x, xhi, BTOK * 256 / 8);

  // ---- fast gate (single f16 MFMA chain) ----
  for (int c = 0; c < CG; c++) {
    const _Float16* xh = xhi + (size_t)c * MC * 256;
    k_gemm_f16<<<dim3(8, MC / 128), tb, 0, stream>>>(xh, g1Th, gb1, h1h, MC, 1024, 256);
    k_gemm_f16<<<dim3(2, MC / 128), tb, 0, stream>>>(h1h, g2Th, gb2,
                                                     h2h + (size_t)c * MC * 256, MC, 256, 1024);
  }
  k_logits<<<BTOK / 128, tb, 0, stream>>>(h2h, g3Th, gb3, logits);
  k_top2<<<BTOK / 256, tb, 0, stream>>>(logits, pout, idx0, idx1, w0a, w1a,
                                        amb2Cnt, amb2List, cnt0, cnt1);

  // ---- tier-2: split-f16 precise gate on near-tie tokens ----
  k_gather2<<<AMB2_CAP / 8, tb, 0, stream>>>(x, amb2Cnt, amb2List, xgh, xgl);
  k_gemm_split<<<dim3(8, AMB2_CAP / 128), tb, 0, stream>>>(
      xgh, xgl, g1Th, g1Tl, gb1, h1gh, h1gl, AMB2_CAP, 1024, 256, amb2Cnt);
  k_gemm_split<<<dim3(2, AMB2_CAP / 128), tb, 0, stream>>>(
      h1gh, h1gl, g2Th, g2Tl, gb2, h2gh, h2gl, AMB2_CAP, 256, 1024, amb2Cnt);
  k_gate3_precise<<<AMB2_CAP / 16, tb, 0, stream>>>(
      h2gh, h2gl, g3, gb3, amb2Cnt, amb2List, pout, idx0, idx1, w0a, w1a,
      amb3Cnt, amb3List, cnt0, cnt1);

  // ---- tier-3: batched parallel fp64 ----
  k_ref_l1<<<dim3(16, AMB3_CAP), tb, 0, stream>>>(x, g1, gb1, amb3Cnt, amb3List, h1d);
  k_ref_l2<<<dim3(4, AMB3_CAP), 512, 0, stream>>>(h1d, g2, gb2, amb3Cnt, h2d);
  k_ref_l3<<<AMB3_CAP, tb, 0, stream>>>(h2d, g3, gb3, amb3Cnt, amb3List,
                                        pout, idx0, idx1, w0a, w1a, cnt0, cnt1);

  // ---- bucket + grouped expert GEMMs ----
  k_offsets<<<1, 64, 0, stream>>>(cnt0, cnt1, off0, off1, cur0, cur1,
                                  dExpC, dRowC, nTiles);
  k_scatter<<<BTOK / 256, tb, 0, stream>>>(idx0, idx1, w0a, w1a, off0, off1,
                                           cur0, cur1, tokAll, wlAll,
                                           tokAll + LCAP, wlAll + LCAP);
  k_grp_l1<<<1056, 512, 0, stream>>>(xhi, bias, W1T, b1, tokAll,
                                     dExpC, dRowC, nTiles + 1, heg);
  k_grp_l2<0><<<528, 512, 0, stream>>>(heg, W2T, b2, tokAll, wlAll,
                                       dExpC, dRowC, nTiles, nTiles + 1, y);
  k_grp_l2<1><<<528, 512, 0, stream>>>(heg, W2T, b2, tokAll, wlAll,
                                       dExpC, dRowC, nTiles, nTiles + 1, y);
}